// Round 5
// baseline (220.829 us; speedup 1.0000x reference)
//
#include <hip/hip_runtime.h>
#include <cstdint>
#include <cstddef>

// B=2, T=4096, C=1024, H=4, G=1, hd=256, window=512, rope base 1e6, eps 1e-6.
#define T_SEQ 4096
#define NB    2
#define CDIM  1024
#define HD    256
#define NH    4

typedef __attribute__((ext_vector_type(8))) __bf16 bf16x8;
typedef __attribute__((ext_vector_type(4))) __bf16 bf16x4;
typedef __attribute__((ext_vector_type(4))) float  floatx4;
typedef __attribute__((ext_vector_type(16))) float f32x16;

__device__ __forceinline__ floatx4 mfma16(bf16x8 a, bf16x8 b, floatx4 c) {
  return __builtin_amdgcn_mfma_f32_16x16x32_bf16(a, b, c, 0, 0, 0);
}
__device__ __forceinline__ f32x16 mfma32(bf16x8 a, bf16x8 b, f32x16 c) {
  return __builtin_amdgcn_mfma_f32_32x32x16_bf16(a, b, c, 0, 0, 0);
}

// async global->LDS, 16B/lane. LDS dest is wave-uniform base + lane*16 (no
// scatter) -- bank-deconflict swizzles are applied to the GLOBAL source
// address (XOR of the 16B-chunk index, stays inside one row's span).
// NOTE (R7 lesson): do NOT replace LDS staging with direct per-fragment global
// loads -- fragment layouts are row-gathers (16 rows x 16B), uncoalesced, 4x
// HBM over-fetch. glds keeps the global side coalesced; LDS does the reshape.
__device__ __forceinline__ void gl2lds16(const void* g, void* l) {
  __builtin_amdgcn_global_load_lds(
      (__attribute__((address_space(1))) void*)g,
      (__attribute__((address_space(3))) void*)l, 16, 0, 0);
}

// ------------------------------------------- fp32 -> bf16, all 5 inputs fused
__global__ __launch_bounds__(256) void cvt_all(const float* __restrict__ x,
                                               const float* __restrict__ wq,
                                               const float* __restrict__ wk,
                                               const float* __restrict__ wv,
                                               const float* __restrict__ wo,
                                               __bf16* __restrict__ xb,
                                               __bf16* __restrict__ wb,
                                               __bf16* __restrict__ wob) {
  int i = blockIdx.x * 256 + threadIdx.x;   // float4 index, [0, 2752512)
  const float* src;
  __bf16* dst;
  int off;
  if (i < 2097152)      { src = x;  dst = xb;            off = i; }
  else if (i < 2359296) { src = wq; dst = wb;            off = i - 2097152; }
  else if (i < 2424832) { src = wk; dst = wb + 1048576;  off = i - 2359296; }
  else if (i < 2490368) { src = wv; dst = wb + 1310720;  off = i - 2424832; }
  else                  { src = wo; dst = wob;           off = i - 2490368; }
  float4 v = ((const float4*)src)[off];
  bf16x4 o;
  o[0] = (__bf16)v.x; o[1] = (__bf16)v.y; o[2] = (__bf16)v.z; o[3] = (__bf16)v.w;
  *(bf16x4*)&dst[(size_t)off * 4] = o;
}

// ------------------------------------------------- C(M,N) = A(M,K) @ B(N,K)^T
// m97 structure + XOR-swizzled LDS (R6-proven). Both A and B staged via
// global_load_lds (coalesced), 128x128 tile, BK=64, 2 barriers/iter,
// 32 KB LDS -> 3 blocks/CU. M,N multiples of 128; K multiple of 64.
template <typename OutT>
__global__ __launch_bounds__(256) void gemm_bt(const __bf16* __restrict__ A,
                                               const __bf16* __restrict__ B,
                                               OutT* __restrict__ C,
                                               int M, int N, int K) {
  __shared__ __bf16 As[128 * 64];
  __shared__ __bf16 Bs[128 * 64];
  const int tid  = threadIdx.x;
  const int lane = tid & 63;
  const int wave = tid >> 6;
  const int wm = wave >> 1, wn = wave & 1;
  const int lrow = lane & 15, quad = lane >> 4;
  const int bm = blockIdx.y, bn = blockIdx.x;

  const __bf16* gA = A + (size_t)(bm * 128) * K;
  const __bf16* gB = B + (size_t)(bn * 128) * K;
  const int arow = tid >> 3;
  const int acol = ((tid & 7) ^ ((tid >> 3) & 7)) * 8;
  const int l7 = lrow & 7;

  floatx4 acc[4][4] = {};

  for (int kt = 0; kt < K; kt += 64) {
#pragma unroll
    for (int i = 0; i < 4; ++i)
      gl2lds16(gA + (size_t)(i * 32 + arow) * K + kt + acol, &As[i * 2048 + tid * 8]);
#pragma unroll
    for (int i = 0; i < 4; ++i)
      gl2lds16(gB + (size_t)(i * 32 + arow) * K + kt + acol, &Bs[i * 2048 + tid * 8]);
    __syncthreads();
#pragma unroll
    for (int kk = 0; kk < 2; ++kk) {
      bf16x8 af[4], bfr[4];
#pragma unroll
      for (int mi = 0; mi < 4; ++mi)
        af[mi] = *(const bf16x8*)&As[(wm * 64 + mi * 16 + lrow) * 64 +
                                     ((kk * 4 + quad) ^ l7) * 8];
#pragma unroll
      for (int ni = 0; ni < 4; ++ni)
        bfr[ni] = *(const bf16x8*)&Bs[(wn * 64 + ni * 16 + lrow) * 64 +
                                      ((kk * 4 + quad) ^ l7) * 8];
#pragma unroll
      for (int mi = 0; mi < 4; ++mi)
#pragma unroll
        for (int ni = 0; ni < 4; ++ni)
          acc[mi][ni] = mfma16(af[mi], bfr[ni], acc[mi][ni]);
    }
    __syncthreads();
  }

  const int row0 = bm * 128 + wm * 64;
  const int col0 = bn * 128 + wn * 64;
#pragma unroll
  for (int mi = 0; mi < 4; ++mi)
#pragma unroll
    for (int ni = 0; ni < 4; ++ni)
#pragma unroll
      for (int r = 0; r < 4; ++r) {
        int row = row0 + mi * 16 + quad * 4 + r;   // C/D: row = quad*4 + reg
        int col = col0 + ni * 16 + lrow;           //      col = lane&15
        C[(size_t)row * N + col] = (OutT)acc[mi][ni][r];
      }
}

// ------------------------------------------------ RMSNorm + RoPE (+ V transpose)
__global__ __launch_bounds__(256) void rmsrope(const __bf16* __restrict__ qkv,
                                               const float* __restrict__ qg,
                                               const float* __restrict__ kg,
                                               __bf16* __restrict__ qr,
                                               __bf16* __restrict__ kr,
                                               __bf16* __restrict__ vt) {
  __shared__ __bf16 Ls[64 * 256];
  if (blockIdx.x >= 5120) {
    const int vb = blockIdx.x - 5120;      // 0..127
    const int b = vb >> 6, tt = vb & 63;
    const int tid = threadIdx.x;
    const __bf16* src = qkv + ((size_t)(b * 4096 + tt * 64)) * 1536 + 1280;
#pragma unroll
    for (int i = 0; i < 8; ++i)
      gl2lds16(src + (size_t)(i * 8 + (tid >> 5)) * 1536 + (tid & 31) * 8,
               &Ls[i * 2048 + tid * 8]);
    __syncthreads();
    __bf16 buf[64];
#pragma unroll
    for (int i = 0; i < 64; ++i) buf[i] = Ls[i * 256 + tid];
    __bf16* dst = vt + ((size_t)(b * 256 + tid)) * T_SEQ + tt * 64;
#pragma unroll
    for (int i = 0; i < 8; ++i)
      *(bf16x8*)&dst[i * 8] = *(const bf16x8*)&buf[i * 8];
    return;
  }

  const int inst = blockIdx.x * 4 + (threadIdx.x >> 6);
  const int lane = threadIdx.x & 63;
  const int rp = inst / 5, which = inst - rp * 5;     // rp in [0, 4096)
  const int row = rp * 2 + (lane >> 5);               // row in [0, 8192)
  const int hl = lane & 31;
  const int b = row >> 12, t = row & 4095;

  const int srcoff = (which < 4) ? which * 256 : 1024;
  const __bf16* src = qkv + (size_t)row * 1536 + srcoff;
  bf16x8 xv = *(const bf16x8*)&src[hl * 8];

  float xf[8];
  float ss = 0.f;
#pragma unroll
  for (int j = 0; j < 8; ++j) { xf[j] = (float)xv[j]; ss += xf[j] * xf[j]; }
#pragma unroll
  for (int off = 16; off >= 1; off >>= 1) ss += __shfl_xor(ss, off);
  const float rms = rsqrtf(ss * (1.0f / 256.0f) + 1e-6f);

  const float* g = (which < 4) ? qg : kg;
  const float4 gv0 = *(const float4*)&g[hl * 8];
  const float4 gv1 = *(const float4*)&g[hl * 8 + 4];
  float y[8];
  y[0] = xf[0] * rms * gv0.x; y[1] = xf[1] * rms * gv0.y;
  y[2] = xf[2] * rms * gv0.z; y[3] = xf[3] * rms * gv0.w;
  y[4] = xf[4] * rms * gv1.x; y[5] = xf[5] * rms * gv1.y;
  y[6] = xf[6] * rms * gv1.z; y[7] = xf[7] * rms * gv1.w;

  const float c_log2 = -19.931568569324174f / 128.0f;  // -log2(1e6)/128
  bf16x8 ov;
#pragma unroll
  for (int j = 0; j < 4; ++j) {
    const int p = hl * 4 + j;
    const float a = (float)t * exp2f((float)p * c_log2);
    const float sn = __sinf(a), cs = __cosf(a);
    ov[2 * j]     = (__bf16)(y[2 * j] * cs - y[2 * j + 1] * sn);
    ov[2 * j + 1] = (__bf16)(y[2 * j] * sn + y[2 * j + 1] * cs);
  }

  __bf16* dst = (which < 4)
      ? qr + ((size_t)((b * NH + which) * T_SEQ) + t) * 256
      : kr + ((size_t)(b * T_SEQ) + t) * 256;
  *(bf16x8*)&dst[hl * 8] = ov;
}

// --------------------------------------------------- flash attention, window=512
// R11: 32x32-MFMA, in-register softmax (T12 family). Evidence: R9 (2x occupancy,
// 0 gain) + R10 (halved LDS ops, -3us) => the 16x16/LDS-P structure's floor is
// {P round-trip + QK<->PV coupling + 2 syncs} x 17 windows. New structure:
//   - 256 blocks (1/CU), 4 waves x 32 queries = QBLK 128; KVBLK=64 -> <=10
//     windows/block, ONE barrier/window, NO P in LDS.
//   - swapped QK^T: s = mfma32(K_frag, Q_frag) -> D[key=crow(r,hi)][q=lane&31];
//     P stays lane-local per q. crow(r,hi) = (r&3)+8*(r>>2)+4*hi (verified D map).
//   - P->PA (PV A-operand, rows q=lane&31, k=hi*8+j): per 32-key tile, 8x
//     v_cvt_pk_bf16_f32 + 4x shfl_xor(.,32) + cndmask. Mapping: pa word wd needs
//     r = kh*8 + hi_t*4 + 2(wd&1) sourced from lane-half (wd>>1).
//   - V^T already global (vt): vf = B-frag directly from LDS, no tr_read.
//   - K/V dbuf (128 KB LDS); gl2lds w/ XOR(chunk, row&7) pre-swizzled source;
//     per-window {stage(wt+1) -> compute(wt) -> vmcnt(0)+lgkmcnt(0)+barrier} --
//     formally correct cross-wave visibility (fixes R10's latent timing race).
//   - XCD map: each XCD = one (b,h) -> 4 MB K+V = its L2.
// Fixed-max softmax (|score|<=16): p = exp2(s*log2e/16 - 16*log2e); l via
// ones-MFMA (lm layout == o layout).
__global__ __launch_bounds__(256, 1) void attn(const __bf16* __restrict__ qr,
                                               const __bf16* __restrict__ kr,
                                               const __bf16* __restrict__ vt,
                                               __bf16* __restrict__ ao) {
  __shared__ __bf16 Ks[2][64 * 256];   // [key][d]   2 x 32 KB
  __shared__ __bf16 Vs[2][256 * 64];   // [d][key]   2 x 32 KB

  const int bid = ((blockIdx.x & 7) << 5) | (blockIdx.x >> 3);
  const int qi = bid & 31, h = (bid >> 5) & 3, b = bid >> 7;
  const int tid = threadIdx.x, w = tid >> 6, lane = tid & 63;
  const int l31 = lane & 31, hi = lane >> 5;

  const __bf16* Q = qr + (size_t)((b * NH + h) * T_SEQ) * 256;
  const __bf16* K = kr + (size_t)(b * T_SEQ) * 256;
  const __bf16* V = vt + (size_t)(b * 256) * T_SEQ;

  const int qbase = qi * 128;
  const int qg = qbase + w * 32 + l31;          // this lane's query row (QK cols)
  const int wt0 = (qi >= 4) ? 2 * qi - 8 : 0;
  const int wt1 = 2 * qi + 1;

  // Q fragments (B-operand, 16 d-steps): qf[s] = Q[qg][s*16 + hi*8 .. +7]
  bf16x8 qf[16];
#pragma unroll
  for (int s = 0; s < 16; ++s)
    qf[s] = *(const bf16x8*)&Q[(size_t)qg * 256 + s * 16 + hi * 8];

  bf16x8 onesv;
#pragma unroll
  for (int j = 0; j < 8; ++j) onesv[j] = (__bf16)1.0f;

  f32x16 o[8] = {};
  f32x16 lm = {};

  const float C1 = 0.09016844005556021f;   // log2(e)/16
  const float C2 = 23.083120654223415f;    // 16*log2(e)

  // ---- staging: wave w stages K rows [w*16,+16) and V rows [w*64,+64).
  // LDS linear dest (gl2lds), global source chunk pre-swizzled: g = c ^ (row&7).
#define STAGE_KV(WT)                                                          \
  {                                                                           \
    const int wt_ = (WT);                                                     \
    __bf16* kd = Ks[wt_ & 1];                                                 \
    __bf16* vd = Vs[wt_ & 1];                                                 \
    _Pragma("unroll")                                                         \
    for (int i = 0; i < 8; ++i) {                                             \
      const int row = (w * 8 + i) * 2 + hi;                                   \
      const int g = l31 ^ (row & 7);                                          \
      gl2lds16(K + (size_t)(wt_ * 64 + row) * 256 + g * 8,                    \
               kd + (w * 8 + i) * 512 + lane * 8);                            \
    }                                                                         \
    _Pragma("unroll")                                                         \
    for (int i = 0; i < 8; ++i) {                                             \
      const int row = (w * 8 + i) * 8 + (lane >> 3);                          \
      const int g = (lane & 7) ^ (row & 7);                                   \
      gl2lds16(V + (size_t)row * T_SEQ + wt_ * 64 + g * 8,                    \
               vd + (w * 8 + i) * 512 + lane * 8);                            \
    }                                                                         \
  }

  // prologue: stage first tile, drain, barrier (all waves' stages visible)
  STAGE_KV(wt0);
  asm volatile("s_waitcnt vmcnt(0)\n\ts_barrier" ::: "memory");

  for (int wt = wt0; wt <= wt1; ++wt) {
    // stage next tile into the other parity (its old content K(wt-1) was
    // fully read by all waves before the previous barrier's lgkmcnt(0))
    if (wt < wt1) STAGE_KV(wt + 1);

    const __bf16* Kb = Ks[wt & 1];
    const __bf16* Vb = Vs[wt & 1];

    // ---- QK^T: s[kt] = K_tile(32 keys) x Q(32 q), accumulate over 16 d-steps
    f32x16 s0 = {}, s1 = {};
#pragma unroll
    for (int s = 0; s < 16; ++s) {
      const int c = ((s * 2 + hi) ^ (l31 & 7)) * 8;
      bf16x8 kf0 = *(const bf16x8*)&Kb[(l31) * 256 + c];
      bf16x8 kf1 = *(const bf16x8*)&Kb[(32 + l31) * 256 + c];
      s0 = mfma32(kf0, qf[s], s0);
      s1 = mfma32(kf1, qf[s], s1);
    }

    // ---- mask + exp (fixed-max): p = exp2(s*C1 - C2)
    const bool full = (wt <= 2 * qi - 1) && (wt >= 2 * qi - 6);
    float p0[16], p1[16];
#pragma unroll
    for (int r = 0; r < 16; ++r) {
      const int crow = (r & 3) + 8 * (r >> 2) + 4 * hi;
      float v0 = s0[r], v1 = s1[r];
      if (!full) {
        const int k0 = wt * 64 + crow;
        const int k1 = k0 + 32;
        v0 = ((k0 <= qg) && (k0 + 512 >= qg)) ? v0 : -1e30f;
        v1 = ((k1 <= qg) && (k1 + 512 >= qg)) ? v1 : -1e30f;
      }
      p0[r] = exp2f(v0 * C1 - C2);
      p1[r] = exp2f(v1 * C1 - C2);
    }

    // ---- P -> PA fragments, fully in-register (cvt_pk + half-wave swap)
    bf16x8 pa[2][2];
#pragma unroll
    for (int kt = 0; kt < 2; ++kt) {
      const float* p = kt ? p1 : p0;
#pragma unroll
      for (int kh = 0; kh < 2; ++kh) {
        unsigned X0, X1, Y0, Y1;
        asm("v_cvt_pk_bf16_f32 %0, %1, %2" : "=v"(X0) : "v"(p[kh * 8 + 0]), "v"(p[kh * 8 + 1]));
        asm("v_cvt_pk_bf16_f32 %0, %1, %2" : "=v"(X1) : "v"(p[kh * 8 + 2]), "v"(p[kh * 8 + 3]));
        asm("v_cvt_pk_bf16_f32 %0, %1, %2" : "=v"(Y0) : "v"(p[kh * 8 + 4]), "v"(p[kh * 8 + 5]));
        asm("v_cvt_pk_bf16_f32 %0, %1, %2" : "=v"(Y1) : "v"(p[kh * 8 + 6]), "v"(p[kh * 8 + 7]));
        const unsigned pX0 = __shfl_xor(X0, 32), pX1 = __shfl_xor(X1, 32);
        const unsigned pY0 = __shfl_xor(Y0, 32), pY1 = __shfl_xor(Y1, 32);
        uint4 wv;
        wv.x = hi ? pY0 : X0;   // keys kh*16 + hi*8 + {0,1}
        wv.y = hi ? pY1 : X1;   //                    {2,3}
        wv.z = hi ? Y0 : pX0;   //                    {4,5}
        wv.w = hi ? Y1 : pX1;   //                    {6,7}
        pa[kt][kh] = __builtin_bit_cast(bf16x8, wv);
      }
    }

    // ---- l accumulation (same D layout as o) + PV
#pragma unroll
    for (int kt = 0; kt < 2; ++kt)
#pragma unroll
      for (int kh = 0; kh < 2; ++kh)
        lm = mfma32(pa[kt][kh], onesv, lm);

#pragma unroll
    for (int n = 0; n < 8; ++n) {
      const int vrow = (n * 32 + l31) * 64;
#pragma unroll
      for (int kt = 0; kt < 2; ++kt)
#pragma unroll
        for (int kh = 0; kh < 2; ++kh) {
          bf16x8 vf = *(const bf16x8*)&Vb[vrow +
                                          (((kt * 4 + kh * 2 + hi) ^ (l31 & 7)) * 8)];
          o[n] = mfma32(pa[kt][kh], vf, o[n]);
        }
    }

    // drain own ds_reads + own next-tile stages, then join
    if (wt < wt1)
      asm volatile("s_waitcnt vmcnt(0) lgkmcnt(0)\n\ts_barrier" ::: "memory");
  }
#undef STAGE_KV

  // ---- epilogue: O/l -> ao in (B,T,H*hd) layout. o/lm rows = q = crow(r,hi),
  // cols = d = n*32 + l31.
#pragma unroll
  for (int r = 0; r < 16; ++r) {
    const float rl = 1.0f / lm[r];
    const int qrow = qbase + w * 32 + (r & 3) + 8 * (r >> 2) + 4 * hi;
#pragma unroll
    for (int n = 0; n < 8; ++n)
      ao[((size_t)(b * T_SEQ + qrow)) * CDIM + h * 256 + n * 32 + l31] =
          (__bf16)(o[n][r] * rl);
  }
}

// -----------------------------------------------------------------------------
extern "C" void kernel_launch(void* const* d_in, const int* in_sizes, int n_in,
                              void* d_out, int out_size, void* d_ws, size_t ws_size,
                              hipStream_t stream) {
  const float* x  = (const float*)d_in[0];
  const float* Wq = (const float*)d_in[1];
  const float* Wk = (const float*)d_in[2];
  const float* Wv = (const float*)d_in[3];
  const float* Wo = (const float*)d_in[4];
  const float* qg = (const float*)d_in[5];
  const float* kg = (const float*)d_in[6];
  float* out = (float*)d_out;

  const size_t M = (size_t)NB * T_SEQ;  // 8192
  char* ws = (char*)d_ws;
  __bf16* xb  = (__bf16*)ws; ws += M * CDIM * 2;
  __bf16* wb  = (__bf16*)ws; ws += (size_t)1536 * CDIM * 2;
  __bf16* wob = (__bf16*)ws; ws += (size_t)CDIM * CDIM * 2;
  __bf16* qkv = (__bf16*)ws; ws += M * 1536 * 2;
  __bf16* qr  = (__bf16*)ws; ws += M * CDIM * 2;
  __bf16* kr  = (__bf16*)ws; ws += M * HD * 2;
  __bf16* vt  = (__bf16*)ws; ws += M * HD * 2;
  __bf16* ao  = (__bf16*)ws;

  // all fp32->bf16 conversions in one launch
  cvt_all<<<10752, 256, 0, stream>>>(x, Wq, Wk, Wv, Wo, xb, wb, wob);

  // QKV projection: (8192 x 1536) = xb @ [Wq;Wk;Wv]^T
  gemm_bt<__bf16><<<dim3(12, 64), 256, 0, stream>>>(xb, wb, qkv, 8192, 1536, 1024);

  // per-head RMSNorm + RoPE on Q,K; V transpose via LDS tiles
  rmsrope<<<5248, 256, 0, stream>>>(qkv, qg, kg, qr, kr, vt);

  // sliding-window flash attention: 128-query blocks, 64-key tiles,
  // 32x32 MFMA + in-register softmax, 1 block/CU
  attn<<<NB * NH * (T_SEQ / 128), 256, 0, stream>>>(qr, kr, vt, ao);

  // output projection to fp32 d_out
  gemm_bt<float><<<dim3(8, 64), 256, 0, stream>>>(ao, wob, out, 8192, 1024, 1024);
}